// Round 1
// baseline (156.240 us; speedup 1.0000x reference)
//
#include <hip/hip_runtime.h>
#include <math.h>

#define T_    128
#define LENM  32
#define NCOL  (8192 * 64)   // N*F = 524288 columns

// Kernel 1: build compact banded softmax weights Wc[128][32] in d_ws.
// Row t mixes source rows src0(t)+j, j=0..31, src0(t)=max(0,t-31).
//  t < 32 : logits = M_pad[t][0..t]    (prefix window, zero-pad j>t)
//  t == 32: logits = M_pad[31][0..31]
//  t > 32 : logits = M_big[t-33][0..31]
__global__ void build_w_kernel(const float* __restrict__ M_pad,
                               const float* __restrict__ M_big,
                               float* __restrict__ Wc) {
    int t = blockIdx.x * blockDim.x + threadIdx.x;
    if (t >= T_) return;
    const float* src;
    int len;
    if (t < LENM)       { src = M_pad + t * LENM;              len = t + 1; }
    else if (t == LENM) { src = M_pad + (LENM - 1) * LENM;     len = LENM; }
    else                { src = M_big + (t - LENM - 1) * LENM; len = LENM; }

    float m = -3.4e38f;
    for (int j = 0; j < len; ++j) m = fmaxf(m, src[j]);
    float e[LENM];
    float s = 0.f;
    for (int j = 0; j < len; ++j) { e[j] = expf(src[j] - m); s += e[j]; }
    float inv = 1.f / s;
    for (int j = 0; j < LENM; ++j)
        Wc[t * LENM + j] = (j < len) ? e[j] * inv : 0.f;
}

// Kernel 2: sliding-window mix along T, one thread per column.
// 4 chunks of 32 timesteps; ping-pong register windows a[]/b[] (fully
// unrolled -> static register indices). Weights are wave-uniform -> s_load.
__global__ __launch_bounds__(256) void band_mix_kernel(
    const float* __restrict__ X,
    const float* __restrict__ Wc,
    float* __restrict__ out) {
    const int c = blockIdx.x * 256 + threadIdx.x;
    const float* xp = X + c;
    float* op = out + c;

    float a[LENM], b[LENM];

    // ---- chunk 0: rows 0..31, src0 = 0, prefix weights (zero-padded) ----
#pragma unroll
    for (int i = 0; i < LENM; ++i) a[i] = xp[(size_t)i * NCOL];
#pragma unroll
    for (int i = 0; i < LENM; ++i) {
        float acc = 0.f;
#pragma unroll
        for (int j = 0; j <= i; ++j)
            acc = fmaf(Wc[i * LENM + j], a[j], acc);
        op[(size_t)i * NCOL] = acc;
    }

    // ---- chunks 1..3: out[32k+i] = sum_j Wc * x[32k+i-31+j] ----
    // window elem j: prev[i+1+j] if i+1+j < 32 else cur[i+j-31]
#define DO_CHUNK(K, CUR, PRV)                                                 \
    {                                                                         \
        _Pragma("unroll")                                                     \
        for (int i = 0; i < LENM; ++i)                                        \
            CUR[i] = xp[(size_t)((K) * LENM + i) * NCOL];                     \
        _Pragma("unroll")                                                     \
        for (int i = 0; i < LENM; ++i) {                                      \
            float acc = 0.f;                                                  \
            _Pragma("unroll")                                                 \
            for (int j = 0; j < LENM; ++j) {                                  \
                float xv = (j < LENM - 1 - i) ? PRV[i + 1 + j]                \
                                              : CUR[i + j - (LENM - 1)];      \
                acc = fmaf(Wc[((K) * LENM + i) * LENM + j], xv, acc);         \
            }                                                                 \
            op[(size_t)((K) * LENM + i) * NCOL] = acc;                        \
        }                                                                     \
    }

    DO_CHUNK(1, b, a)
    DO_CHUNK(2, a, b)
    DO_CHUNK(3, b, a)
#undef DO_CHUNK
}

extern "C" void kernel_launch(void* const* d_in, const int* in_sizes, int n_in,
                              void* d_out, int out_size, void* d_ws, size_t ws_size,
                              hipStream_t stream) {
    const float* X     = (const float*)d_in[0];
    const float* M_pad = (const float*)d_in[1];
    const float* M_big = (const float*)d_in[2];
    float* out = (float*)d_out;
    float* Wc  = (float*)d_ws;   // 128*32*4 = 16 KB scratch

    build_w_kernel<<<1, 128, 0, stream>>>(M_pad, M_big, Wc);
    band_mix_kernel<<<NCOL / 256, 256, 0, stream>>>(X, Wc, out);
}

// Round 2
// 101.426 us; speedup vs baseline: 1.5404x; 1.5404x over previous
//
#include <hip/hip_runtime.h>
#include <math.h>

#define T_    128
#define LENM  32
#define NCOL  (8192 * 64)   // N*F = 524288 floats per timestep row

typedef float f2 __attribute__((ext_vector_type(2)));

// Kernel 1: build ALIGNED compact weights Wc[128][32] in d_ws.
// Wc[t][j] multiplies source row (t-31+j); zero when that row < 0.
//  t < 32 : softmax(M_pad[t][0..t]) lands at j = 31-t .. 31
//  t == 32: softmax(M_pad[31][0..31]) at j = 0..31 (source rows 1..32)
//  t > 32 : softmax(M_big[t-33][0..31]) at j = 0..31
__global__ void build_w_kernel(const float* __restrict__ M_pad,
                               const float* __restrict__ M_big,
                               float* __restrict__ Wc) {
    int t = threadIdx.x;
    if (t >= T_) return;
    const float* src;
    int len, joff;
    if (t < LENM)       { src = M_pad + t * LENM;              len = t + 1; joff = LENM - 1 - t; }
    else if (t == LENM) { src = M_pad + (LENM - 1) * LENM;     len = LENM;  joff = 0; }
    else                { src = M_big + (t - LENM - 1) * LENM; len = LENM;  joff = 0; }

    float m = -3.4e38f;
    for (int j = 0; j < len; ++j) m = fmaxf(m, src[j]);
    float e[LENM];
    float s = 0.f;
    for (int j = 0; j < len; ++j) { e[j] = expf(src[j] - m); s += e[j]; }
    float inv = 1.f / s;
    for (int j = 0; j < LENM; ++j) Wc[t * LENM + j] = 0.f;
    for (int j = 0; j < len; ++j)  Wc[t * LENM + joff + j] = e[j] * inv;
}

// Kernel 2: sliding-window mix along T. Each thread owns 2 adjacent columns
// (float2). 4 chunks of 32 rows, ping-pong register windows (fully unrolled,
// static indices). Weights staged in LDS, read via uniform-address
// ds_read_b128 (broadcast). Initial window = zeros (weights are zero there).
__global__ __launch_bounds__(256) void band_mix_kernel(
    const float* __restrict__ X,
    const float* __restrict__ Wc,
    float* __restrict__ out) {
    __shared__ float4 w4[T_ * LENM / 4];   // 1024 float4 = 16 KB
    for (int i = threadIdx.x; i < T_ * LENM / 4; i += 256)
        w4[i] = reinterpret_cast<const float4*>(Wc)[i];
    __syncthreads();

    const int c = (blockIdx.x * 256 + threadIdx.x) * 2;
    const f2* xp = reinterpret_cast<const f2*>(X + c);
    f2* op = reinterpret_cast<f2*>(out + c);
    const size_t rs = NCOL / 2;   // row stride in f2 units

    f2 a[LENM], b[LENM];
#pragma unroll
    for (int i = 0; i < LENM; ++i) { a[i].x = 0.f; a[i].y = 0.f; }

#define DO_CHUNK(K, CUR, PRV)                                                 \
    {                                                                         \
        _Pragma("unroll")                                                     \
        for (int i = 0; i < LENM; ++i)                                        \
            CUR[i] = xp[(size_t)((K) * LENM + i) * rs];                       \
        _Pragma("unroll")                                                     \
        for (int i = 0; i < LENM; ++i) {                                      \
            const int row = (K) * LENM + i;                                   \
            f2 acc; acc.x = 0.f; acc.y = 0.f;                                 \
            _Pragma("unroll")                                                 \
            for (int q = 0; q < 8; ++q) {                                     \
                float4 w = w4[row * 8 + q];                                   \
                _Pragma("unroll")                                             \
                for (int m = 0; m < 4; ++m) {                                 \
                    const int j = q * 4 + m;                                  \
                    float wm = (m == 0) ? w.x : (m == 1) ? w.y                \
                             : (m == 2) ? w.z : w.w;                          \
                    f2 xv = (j < LENM - 1 - i) ? PRV[i + 1 + j]               \
                                               : CUR[i + j - (LENM - 1)];     \
                    acc.x = fmaf(wm, xv.x, acc.x);                            \
                    acc.y = fmaf(wm, xv.y, acc.y);                            \
                }                                                             \
            }                                                                 \
            __builtin_nontemporal_store(acc, &op[(size_t)row * rs]);          \
        }                                                                     \
    }

    DO_CHUNK(0, b, a)
    DO_CHUNK(1, a, b)
    DO_CHUNK(2, b, a)
    DO_CHUNK(3, a, b)
#undef DO_CHUNK
}

extern "C" void kernel_launch(void* const* d_in, const int* in_sizes, int n_in,
                              void* d_out, int out_size, void* d_ws, size_t ws_size,
                              hipStream_t stream) {
    const float* X     = (const float*)d_in[0];
    const float* M_pad = (const float*)d_in[1];
    const float* M_big = (const float*)d_in[2];
    float* out = (float*)d_out;
    float* Wc  = (float*)d_ws;   // 128*32*4 = 16 KB scratch

    build_w_kernel<<<1, 128, 0, stream>>>(M_pad, M_big, Wc);
    band_mix_kernel<<<NCOL / 2 / 256, 256, 0, stream>>>(X, Wc, out);
}

// Round 4
// 95.318 us; speedup vs baseline: 1.6391x; 1.0641x over previous
//
#include <hip/hip_runtime.h>
#include <math.h>

#define T_    128
#define LENM  32
#define NCOL  (8192 * 64)   // N*F = 524288 floats per timestep row

typedef float f4_t __attribute__((ext_vector_type(4)));

// Kernel 1: build ALIGNED compact weights Wc[128][32] in d_ws.
// Wc[t][j] multiplies source row (t-31+j); zero when that row < 0.
__global__ void build_w_kernel(const float* __restrict__ M_pad,
                               const float* __restrict__ M_big,
                               float* __restrict__ Wc) {
    int t = threadIdx.x;
    if (t >= T_) return;
    const float* src;
    int len, joff;
    if (t < LENM)       { src = M_pad + t * LENM;              len = t + 1; joff = LENM - 1 - t; }
    else if (t == LENM) { src = M_pad + (LENM - 1) * LENM;     len = LENM;  joff = 0; }
    else                { src = M_big + (t - LENM - 1) * LENM; len = LENM;  joff = 0; }

    float m = -3.4e38f;
    for (int j = 0; j < len; ++j) m = fmaxf(m, src[j]);
    float e[LENM];
    float s = 0.f;
    for (int j = 0; j < len; ++j) { e[j] = expf(src[j] - m); s += e[j]; }
    float inv = 1.f / s;
    for (int j = 0; j < LENM; ++j) Wc[t * LENM + j] = 0.f;
    for (int j = 0; j < len; ++j)  Wc[t * LENM + joff + j] = e[j] * inv;
}

// One pipeline step for output row R (compile-time). Chunk K = R/32 uses
// window buffer CUR=(K&1?B:A), previous chunk's buffer is PRV. Issues the
// global load of row R+8 into its statically-known slot, then computes
// output R from 32 banded taps (prefix-zero taps skipped at compile time)
// and stores it nontemporally.
template<int R>
__device__ __forceinline__ void step(const f4_t* __restrict__ xp,
                                     f4_t* __restrict__ op,
                                     const f4_t* w4,
                                     f4_t (&A)[LENM], f4_t (&B)[LENM]) {
    constexpr int K     = R / LENM;
    constexpr int i_    = R % LENM;
    constexpr int jmin_ = (R < LENM) ? (LENM - 1 - i_) : 0;
    f4_t (&CUR)[LENM] = (K & 1) ? B : A;
    f4_t (&PRV)[LENM] = (K & 1) ? A : B;
    const size_t rs = NCOL / 4;   // row stride in f4 units

    if constexpr (R + 8 < T_) {
        f4_t ld = xp[(size_t)(R + 8) * rs];
        if constexpr (i_ < LENM - 8) CUR[i_ + 8] = ld;   // row R+8 in same chunk
        else                         PRV[i_ - (LENM - 8)] = ld;  // next chunk's buffer
    }

    f4_t acc; acc.x = 0.f; acc.y = 0.f; acc.z = 0.f; acc.w = 0.f;
#pragma unroll
    for (int q = 0; q < 8; ++q) {
        if (q * 4 + 3 >= jmin_) {            // folds: q, jmin_ are constants
            f4_t w = w4[R * 8 + q];
#pragma unroll
            for (int m = 0; m < 4; ++m) {
                const int j = q * 4 + m;
                if (j >= jmin_) {
                    f4_t xv = (j < LENM - 1 - i_) ? PRV[i_ + 1 + j]
                                                  : CUR[i_ + j - (LENM - 1)];
                    float wm = (m == 0) ? w.x : (m == 1) ? w.y
                             : (m == 2) ? w.z : w.w;
                    acc.x = fmaf(wm, xv.x, acc.x);
                    acc.y = fmaf(wm, xv.y, acc.y);
                    acc.z = fmaf(wm, xv.z, acc.z);
                    acc.w = fmaf(wm, xv.w, acc.w);
                }
            }
        }
    }
    __builtin_nontemporal_store(acc, &op[(size_t)R * rs]);
}

template<int R>
__device__ __forceinline__ void run_steps(const f4_t* __restrict__ xp,
                                          f4_t* __restrict__ op,
                                          const f4_t* w4,
                                          f4_t (&A)[LENM], f4_t (&B)[LENM]) {
    if constexpr (R < T_) {
        step<R>(xp, op, w4, A, B);
        run_steps<R + 1>(xp, op, w4, A, B);
    }
}

// Kernel 2: sliding-window mix. Each thread owns 4 adjacent columns (float4).
// Flat 128-step software pipeline with 8-row lookahead; ping-pong register
// windows A/B, all indices compile-time (template recursion).
__global__ __launch_bounds__(256, 2) void band_mix_kernel(
    const float* __restrict__ X,
    const float* __restrict__ Wc,
    float* __restrict__ out) {
    __shared__ f4_t w4[T_ * LENM / 4];   // 1024 f4 = 16 KB
    for (int i = threadIdx.x; i < T_ * LENM / 4; i += 256)
        w4[i] = reinterpret_cast<const f4_t*>(Wc)[i];
    __syncthreads();

    const int c = (blockIdx.x * 256 + threadIdx.x) * 4;
    const f4_t* xp = reinterpret_cast<const f4_t*>(X + c);
    f4_t* op = reinterpret_cast<f4_t*>(out + c);
    const size_t rs = NCOL / 4;

    f4_t A[LENM], B[LENM];
    // prologue: rows 0..7 into A (chunk 0 never reads PRV; B needs no init)
#pragma unroll
    for (int i = 0; i < 8; ++i) A[i] = xp[(size_t)i * rs];

    run_steps<0>(xp, op, w4, A, B);
}

extern "C" void kernel_launch(void* const* d_in, const int* in_sizes, int n_in,
                              void* d_out, int out_size, void* d_ws, size_t ws_size,
                              hipStream_t stream) {
    const float* X     = (const float*)d_in[0];
    const float* M_pad = (const float*)d_in[1];
    const float* M_big = (const float*)d_in[2];
    float* out = (float*)d_out;
    float* Wc  = (float*)d_ws;   // 128*32*4 = 16 KB scratch

    build_w_kernel<<<1, 128, 0, stream>>>(M_pad, M_big, Wc);
    band_mix_kernel<<<NCOL / 4 / 256, 256, 0, stream>>>(X, Wc, out);
}